// Round 10
// baseline (190.058 us; speedup 1.0000x reference)
//
#include <hip/hip_runtime.h>
#include <stdint.h>

#define NB 16
#define NC 128
#define NOC 128
#define NF 64
#define NT 256
#define NCTX 128
#define NTAPS 9
#define NFLAT 147456
#define TEMPR 30.0f

// LDS: X only. 16B chunk = 8 bf16 ic elems. chunks [r:3][kq:4][colp:130]
// colp = col ^ (kq>>1)  -- bank-spreading XOR, bijective on 0..129
#define SXCOLS 130
#define SX_CH (3*4*SXCOLS)    // 1560 chunks = 24960 B

typedef float f32x4 __attribute__((ext_vector_type(4)));
typedef __bf16 bf16x8 __attribute__((ext_vector_type(8)));

// ---------------- kernel 1: attention (16 x softmax over 4) ----------------
__global__ void attn_kernel(const float* __restrict__ g,
                            const float* __restrict__ dk,
                            const float* __restrict__ bias,
                            float* __restrict__ att) {
    int b = threadIdx.x;
    if (b >= NB) return;
    float r0 = bias[0], r1 = bias[1], r2 = bias[2], r3 = bias[3];
    const float* gb = g + b * NCTX;
    for (int c = 0; c < NCTX; ++c) {
        float gv = gb[c];
        r0 += gv * dk[c*4+0];
        r1 += gv * dk[c*4+1];
        r2 += gv * dk[c*4+2];
        r3 += gv * dk[c*4+3];
    }
    r0 *= (1.0f/TEMPR); r1 *= (1.0f/TEMPR); r2 *= (1.0f/TEMPR); r3 *= (1.0f/TEMPR);
    float mx = fmaxf(fmaxf(r0, r1), fmaxf(r2, r3));
    float e0 = expf(r0-mx), e1 = expf(r1-mx), e2 = expf(r2-mx), e3 = expf(r3-mx);
    float s = e0+e1+e2+e3;
    att[b*4+0] = e0/s; att[b*4+1] = e1/s; att[b*4+2] = e2/s; att[b*4+3] = e3/s;
}

// ------- kernel 2: blend 4 banks -> bf16 W K-major: [b][c4:4][tap:9][kq:4][oc:128][8]
// A lane's MFMA A-fragment (oc, k=kq*8+e) is one contiguous 16B chunk.
__global__ void agg_kernel(const float* __restrict__ w,
                           const float* __restrict__ att,
                           unsigned short* __restrict__ wb) {
    int idx = blockIdx.x * 256 + threadIdx.x;   // 16*128*128 = 262144
    int ic = idx & 127;
    int oc = (idx >> 7) & 127;
    int b  = idx >> 14;
    float a0 = att[b*4+0], a1 = att[b*4+1], a2 = att[b*4+2], a3 = att[b*4+3];
    int d0 = (oc*NC + ic) * NTAPS;
    int c4 = ic >> 5;
    int kq = (ic >> 3) & 3;
    int e  = ic & 7;
    #pragma unroll
    for (int tap = 0; tap < NTAPS; ++tap) {
        float s = a0 * w[0*NFLAT + d0 + tap]
                + a1 * w[1*NFLAT + d0 + tap]
                + a2 * w[2*NFLAT + d0 + tap]
                + a3 * w[3*NFLAT + d0 + tap];
        __bf16 h = (__bf16)s;
        unsigned short u = *(unsigned short*)&h;
        int chunk = (tap * 4 + kq) * 128 + oc;                    // within c4 block
        wb[(((b * 4 + c4) * (NTAPS*4*NOC)) + chunk) * 8 + e] = u;
    }
}

// ------------------- kernel 3: MFMA implicit-GEMM conv -------------------
// R6's proven deep prefetch + R9's W-from-L2 + fixes:
//  - X global loads for c4+1 prefetched into regs during c4's compute (T14)
//  - A-fragments from L2 (K-major panel, XCD-resident) via 3-tap-deep register
//    ring (~234cy cover >= L2 latency; R9's 1-tap ring stalled every tap)
//  - X LDS writes bank-spread via colp = col ^ (kq>>1): 2-way max (was 4-way,
//    8 extra cyc on all 786k write instrs = the constant 6.29e6 counter)
// LDS = 25KB (X only); 256-thr blocks -> 2 desynced blocks/CU at 2 waves/SIMD.
__global__ __launch_bounds__(256) void conv_kernel(
        const float* __restrict__ x,
        const unsigned short* __restrict__ wb,
        float* __restrict__ out) {
    __shared__ __align__(16) unsigned short sx[SX_CH * 8];

    // bijective XCD swizzle: 2048 blocks -> 256 contiguous logical per XCD = 2 batches
    const int p_  = blockIdx.x;
    const int lg  = (p_ & 7) * 256 + (p_ >> 3);
    const int b   = lg >> 7;            // batch
    const int y   = (lg >> 1) & 63;     // output row
    const int t0  = (lg & 1) * 128;     // t half

    const int tid  = threadIdx.x;
    const int lane = tid & 63;
    const int wid  = tid >> 6;
    const int wpix = wid & 1;    // 64-pix half
    const int woc  = wid >> 1;   // 64-oc half
    const int l15  = lane & 15;
    const int l4   = lane >> 4;

    f32x4 acc[4][4];
    #pragma unroll
    for (int m = 0; m < 4; ++m)
        #pragma unroll
        for (int n = 0; n < 4; ++n)
            acc[m][n] = (f32x4){0.f, 0.f, 0.f, 0.f};

    const float* xb = x + (b * NC) * (NF * NT);
    const unsigned short* wbb = wb + b * (4 * NTAPS * 4 * NOC) * 8;
    // per-lane A offset (shorts): chunk (l4*128 + woc*64 + m*16 + l15) within slice
    const int wlane = (l4 * 128 + woc * 64 + l15) * 8;

    // X staging decomposition: unit u = tid + j*256 (j<6):
    //   e=u&3 (ic pair), kq=(u>>2)&3, q=(u>>4)&31, r=u>>9
    const int se  = tid & 3;
    const int skq = (tid >> 2) & 3;
    const int sd  = skq >> 1;          // write-side XOR bit

    // read-side: per-lane kx col offsets with the same XOR (l4 = k-quarter)
    const int rd  = l4 >> 1;
    int cb0 = (wpix * 64 + l15 + 0) ^ rd;
    int cb1 = (wpix * 64 + l15 + 1) ^ rd;
    int cb2 = (wpix * 64 + l15 + 2) ^ rd;

    // prefetch registers
    f32x4 xv0[6], xv1[6];
    float bf0 = 0.f, bf1 = 0.f;
    bf16x8 ar0[4], ar1[4], ar2[4];

    auto issue_x = [&](int c4) {
        const int ic = c4 * 32 + skq * 8 + se * 2;
        #pragma unroll
        for (int j = 0; j < 6; ++j) {
            const int u = tid + j * 256;
            const int q = (u >> 4) & 31;
            const int r = u >> 9;
            const int iy = y - 1 + r;
            f32x4 v0 = (f32x4){0.f,0.f,0.f,0.f};
            f32x4 v1 = v0;
            if ((unsigned)iy < (unsigned)NF) {
                const float* src = xb + (ic * NF + iy) * NT + t0 + q * 4;
                v0 = *(const f32x4*)src;
                v1 = *(const f32x4*)(src + NF * NT);
            }
            xv0[j] = v0;
            xv1[j] = v1;
        }
        bf0 = 0.f; bf1 = 0.f;
        if (tid < 96) {
            const int e    = tid & 3;
            const int kq   = (tid >> 2) & 3;
            const int side = (tid >> 4) & 1;
            const int r    = tid >> 5;           // 0..2
            const int t    = side ? (t0 + 128) : (t0 - 1);
            const int iy   = y - 1 + r;
            const int ic   = c4 * 32 + kq * 8 + e * 2;
            if ((unsigned)iy < (unsigned)NF && (unsigned)t < (unsigned)NT) {
                const float* src = xb + (ic * NF + iy) * NT + t;
                bf0 = src[0];
                bf1 = src[NF * NT];
            }
        }
    };

    auto write_x = [&]() {
        #pragma unroll
        for (int j = 0; j < 6; ++j) {
            const int u = tid + j * 256;
            const int q = (u >> 4) & 31;
            const int r = u >> 9;
            unsigned short* base = sx + ((r * 4 + skq) * SXCOLS) * 8 + se * 2;
            #pragma unroll
            for (int jj = 0; jj < 4; ++jj) {
                const int colp = (q * 4 + 1 + jj) ^ sd;
                __bf16 h0 = (__bf16)xv0[j][jj];
                __bf16 h1 = (__bf16)xv1[j][jj];
                unsigned pk = (unsigned)*(unsigned short*)&h0
                            | ((unsigned)*(unsigned short*)&h1 << 16);
                *(unsigned*)(base + colp * 8) = pk;
            }
        }
        if (tid < 96) {
            const int e    = tid & 3;
            const int kq   = (tid >> 2) & 3;
            const int side = (tid >> 4) & 1;
            const int r    = tid >> 5;
            const int colp = (side ? (SXCOLS - 1) : 0) ^ (kq >> 1);
            __bf16 h0 = (__bf16)bf0;
            __bf16 h1 = (__bf16)bf1;
            unsigned pk = (unsigned)*(unsigned short*)&h0
                        | ((unsigned)*(unsigned short*)&h1 << 16);
            *(unsigned*)(sx + ((r * 4 + kq) * SXCOLS + colp) * 8 + e * 2) = pk;
        }
    };

    auto loadA = [&](bf16x8* dst, int c4, int tap) {
        const unsigned short* wt = wbb + ((c4 * NTAPS + tap) * 4 * NOC) * 8 + wlane;
        dst[0] = *(const bf16x8*)(wt);
        dst[1] = *(const bf16x8*)(wt + 16 * 8);
        dst[2] = *(const bf16x8*)(wt + 32 * 8);
        dst[3] = *(const bf16x8*)(wt + 48 * 8);
    };

    // ---- prologue: stage c4=0 X, A taps 0-2
    issue_x(0);
    loadA(ar0, 0, 0);
    loadA(ar1, 0, 1);
    loadA(ar2, 0, 2);
    write_x();
    __syncthreads();

    for (int c4 = 0; c4 < 4; ++c4) {
        if (c4 < 3) issue_x(c4 + 1);   // next X flies under this c4's compute

        // ---- compute: 9 taps, A ring 3 deep, B from LDS
        #pragma unroll
        for (int tap = 0; tap < 9; ++tap) {
            bf16x8* cur = (tap % 3 == 0) ? ar0 : (tap % 3 == 1) ? ar1 : ar2;
            const int ky = tap / 3;
            const int kx = tap % 3;
            const int cbk = (kx == 0) ? cb0 : (kx == 1) ? cb1 : cb2;
            bf16x8 bfv[4];
            #pragma unroll
            for (int n = 0; n < 4; ++n)
                bfv[n] = *(const bf16x8*)(sx + (((ky * 4 + l4) * SXCOLS) + cbk + n * 16) * 8);
            #pragma unroll
            for (int n = 0; n < 4; ++n) {
                acc[0][n] = __builtin_amdgcn_mfma_f32_16x16x32_bf16(cur[0], bfv[n], acc[0][n], 0, 0, 0);
                acc[1][n] = __builtin_amdgcn_mfma_f32_16x16x32_bf16(cur[1], bfv[n], acc[1][n], 0, 0, 0);
                acc[2][n] = __builtin_amdgcn_mfma_f32_16x16x32_bf16(cur[2], bfv[n], acc[2][n], 0, 0, 0);
                acc[3][n] = __builtin_amdgcn_mfma_f32_16x16x32_bf16(cur[3], bfv[n], acc[3][n], 0, 0, 0);
            }
            if (tap < 6) loadA(cur, c4, tap + 3);   // refill ring 3 taps ahead
        }

        if (c4 < 3) {
            // A taps 0-2 of next c4: latency hidden by barrier drain + ds_writes
            loadA(ar0, c4 + 1, 0);
            loadA(ar1, c4 + 1, 1);
            loadA(ar2, c4 + 1, 2);
            __syncthreads();           // all waves done reading sx
            write_x();
            __syncthreads();
        }
    }

    // ---- epilogue: D[row=oc=(l>>4)*4+r][col=pix=l&15]
    #pragma unroll
    for (int m = 0; m < 4; ++m) {
        int ocb = woc * 64 + m * 16 + l4 * 4;
        #pragma unroll
        for (int r = 0; r < 4; ++r) {
            float* orow = out + ((b * NOC + ocb + r) * NF + y) * NT + t0;
            #pragma unroll
            for (int n = 0; n < 4; ++n)
                orow[wpix * 64 + n * 16 + l15] = acc[m][n][r];
        }
    }
}

extern "C" void kernel_launch(void* const* d_in, const int* in_sizes, int n_in,
                              void* d_out, int out_size, void* d_ws, size_t ws_size,
                              hipStream_t stream) {
    const float* x    = (const float*)d_in[0];
    const float* g    = (const float*)d_in[1];
    const float* dk   = (const float*)d_in[2];
    const float* bias = (const float*)d_in[3];
    const float* w    = (const float*)d_in[4];
    float* out = (float*)d_out;

    float* att = (float*)d_ws;                                  // 64 floats
    unsigned short* wb = (unsigned short*)((char*)d_ws + 256);  // 16*9*128*128 bf16, K-major

    attn_kernel<<<dim3(1), dim3(64), 0, stream>>>(g, dk, bias, att);
    agg_kernel<<<dim3(1024), dim3(256), 0, stream>>>(w, att, wb);
    conv_kernel<<<dim3(2048), dim3(256), 0, stream>>>(x, wb, out);
}

// Round 11
// 135.486 us; speedup vs baseline: 1.4028x; 1.4028x over previous
//
#include <hip/hip_runtime.h>
#include <stdint.h>

#define NB 16
#define NC 128
#define NOC 128
#define NF 64
#define NT 256
#define NCTX 128
#define NTAPS 9
#define NFLAT 147456
#define TEMPR 30.0f

// LDS: X only, K-major 16B chunks (8 bf16 ic elems).
// chunk index = (r*4 + kq)*SXSTRIDE + col ; col 0..129 (t = t0-1+col), 1 pad col.
// Odd stride 131 -> X u32 writes hit all 32 banks (2-way = free);
// power-of-2-ish strides (R5-R10) were a structural 4-way (the constant 6.29e6).
#define SXCOLS 130
#define SXSTRIDE 131
#define SX_CH (12*SXSTRIDE)   // 1572 chunks = 25152 B

typedef float f32x4 __attribute__((ext_vector_type(4)));
typedef __bf16 bf16x8 __attribute__((ext_vector_type(8)));

// ---------------- kernel 1: attention (16 x softmax over 4) ----------------
__global__ void attn_kernel(const float* __restrict__ g,
                            const float* __restrict__ dk,
                            const float* __restrict__ bias,
                            float* __restrict__ att) {
    int b = threadIdx.x;
    if (b >= NB) return;
    float r0 = bias[0], r1 = bias[1], r2 = bias[2], r3 = bias[3];
    const float* gb = g + b * NCTX;
    for (int c = 0; c < NCTX; ++c) {
        float gv = gb[c];
        r0 += gv * dk[c*4+0];
        r1 += gv * dk[c*4+1];
        r2 += gv * dk[c*4+2];
        r3 += gv * dk[c*4+3];
    }
    r0 *= (1.0f/TEMPR); r1 *= (1.0f/TEMPR); r2 *= (1.0f/TEMPR); r3 *= (1.0f/TEMPR);
    float mx = fmaxf(fmaxf(r0, r1), fmaxf(r2, r3));
    float e0 = expf(r0-mx), e1 = expf(r1-mx), e2 = expf(r2-mx), e3 = expf(r3-mx);
    float s = e0+e1+e2+e3;
    att[b*4+0] = e0/s; att[b*4+1] = e1/s; att[b*4+2] = e2/s; att[b*4+3] = e3/s;
}

// ------- kernel 2: blend 4 banks -> bf16 W K-major: [b][c4:4][tap:9][kq:4][oc:128][8]
// A lane's MFMA A-fragment (oc, k=kq*8+e) is one contiguous 16B chunk.
__global__ void agg_kernel(const float* __restrict__ w,
                           const float* __restrict__ att,
                           unsigned short* __restrict__ wb) {
    int idx = blockIdx.x * 256 + threadIdx.x;   // 16*128*128 = 262144
    int ic = idx & 127;
    int oc = (idx >> 7) & 127;
    int b  = idx >> 14;
    float a0 = att[b*4+0], a1 = att[b*4+1], a2 = att[b*4+2], a3 = att[b*4+3];
    int d0 = (oc*NC + ic) * NTAPS;
    int c4 = ic >> 5;
    int kq = (ic >> 3) & 3;
    int e  = ic & 7;
    #pragma unroll
    for (int tap = 0; tap < NTAPS; ++tap) {
        float s = a0 * w[0*NFLAT + d0 + tap]
                + a1 * w[1*NFLAT + d0 + tap]
                + a2 * w[2*NFLAT + d0 + tap]
                + a3 * w[3*NFLAT + d0 + tap];
        __bf16 h = (__bf16)s;
        unsigned short u = *(unsigned short*)&h;
        int chunk = (tap * 4 + kq) * 128 + oc;                    // within c4 block
        wb[(((b * 4 + c4) * (NTAPS*4*NOC)) + chunk) * 8 + e] = u;
    }
}

// ------------------- kernel 3: MFMA implicit-GEMM conv -------------------
// W from L2 (no W LDS: halves LDS traffic; R9-proven) via depth-2 A ring in
// NAMED arrays, literal indices only, hand-sequenced taps (R10's dynamic ring
// selection wrecked codegen). X reg-prefetched one c4 ahead (R6-proven T14).
// LDS 25KB (X only, stride-131 conflict-free); 256 thr -> 2 desynced blocks/CU.
__global__ __launch_bounds__(256) void conv_kernel(
        const float* __restrict__ x,
        const unsigned short* __restrict__ wb,
        float* __restrict__ out) {
    __shared__ __align__(16) unsigned short sx[SX_CH * 8];

    // bijective XCD swizzle: 2048 blocks -> 256 contiguous logical per XCD = 2 batches
    const int p_  = blockIdx.x;
    const int lg  = (p_ & 7) * 256 + (p_ >> 3);
    const int b   = lg >> 7;            // batch
    const int y   = (lg >> 1) & 63;     // output row
    const int t0  = (lg & 1) * 128;     // t half

    const int tid  = threadIdx.x;
    const int lane = tid & 63;
    const int wid  = tid >> 6;
    const int wpix = wid & 1;    // 64-pix half
    const int woc  = wid >> 1;   // 64-oc half
    const int l15  = lane & 15;
    const int l4   = lane >> 4;

    f32x4 acc[4][4];
    #pragma unroll
    for (int m = 0; m < 4; ++m)
        #pragma unroll
        for (int n = 0; n < 4; ++n)
            acc[m][n] = (f32x4){0.f, 0.f, 0.f, 0.f};

    const float* xb = x + (b * NC) * (NF * NT);
    // per-thread A base: chunk (l4*128 + woc*64 + l15) within a (c4,tap) slice
    const unsigned short* const wbase =
        wb + b * (NTAPS * NOC * NC) + (l4 * 128 + woc * 64 + l15) * 8;
    // per-thread B base (compute)
    const unsigned short* const sxp = sx + (l4 * SXSTRIDE + wpix * 64 + l15) * 8;

    // X staging decomposition: unit u = tid + j*256 (j<6):
    //   e=u&3 (ic pair), kq=(u>>2)&3, q=(u>>4)&31 (4-col group), r=u>>9 (row)
    const int se  = tid & 3;
    const int skq = (tid >> 2) & 3;

    f32x4 xv0[6], xv1[6];
    float bf0 = 0.f, bf1 = 0.f;
    bf16x8 A0[4], A1[4];

    auto issue_x = [&](int c4) {
        const int ic = c4 * 32 + skq * 8 + se * 2;
        #pragma unroll
        for (int j = 0; j < 6; ++j) {
            const int u = tid + j * 256;
            const int q = (u >> 4) & 31;
            const int r = u >> 9;
            const int iy = y - 1 + r;
            f32x4 v0 = (f32x4){0.f,0.f,0.f,0.f};
            f32x4 v1 = v0;
            if ((unsigned)iy < (unsigned)NF) {
                const float* src = xb + (ic * NF + iy) * NT + t0 + q * 4;
                v0 = *(const f32x4*)src;
                v1 = *(const f32x4*)(src + NF * NT);
            }
            xv0[j] = v0;
            xv1[j] = v1;
        }
        bf0 = 0.f; bf1 = 0.f;
        if (tid < 96) {
            const int side = (tid >> 4) & 1;
            const int r    = tid >> 5;           // 0..2
            const int t    = side ? (t0 + 128) : (t0 - 1);
            const int iy   = y - 1 + r;
            if ((unsigned)iy < (unsigned)NF && (unsigned)t < (unsigned)NT) {
                const float* src = xb + (ic * NF + iy) * NT + t;
                bf0 = src[0];
                bf1 = src[NF * NT];
            }
        }
    };

    auto write_x = [&]() {
        #pragma unroll
        for (int j = 0; j < 6; ++j) {
            const int u = tid + j * 256;
            const int q = (u >> 4) & 31;
            const int r = u >> 9;
            unsigned short* dst =
                sx + ((r * 4 + skq) * SXSTRIDE + q * 4 + 1) * 8 + se * 2;
            #pragma unroll
            for (int jj = 0; jj < 4; ++jj) {
                __bf16 h0 = (__bf16)xv0[j][jj];
                __bf16 h1 = (__bf16)xv1[j][jj];
                unsigned pk = (unsigned)*(unsigned short*)&h0
                            | ((unsigned)*(unsigned short*)&h1 << 16);
                *(unsigned*)(dst + jj * 8) = pk;   // next col = +1 chunk
            }
        }
        if (tid < 96) {
            const int side = (tid >> 4) & 1;
            const int r    = tid >> 5;
            const int col  = side ? (SXCOLS - 1) : 0;
            __bf16 h0 = (__bf16)bf0;
            __bf16 h1 = (__bf16)bf1;
            unsigned pk = (unsigned)*(unsigned short*)&h0
                        | ((unsigned)*(unsigned short*)&h1 << 16);
            *(unsigned*)(sx + ((r * 4 + skq) * SXSTRIDE + col) * 8 + se * 2) = pk;
        }
    };

    auto loadA = [&](bf16x8* dst, int c4, int tap) {
        const unsigned short* wt = wbase + (c4 * NTAPS + tap) * 4096;
        dst[0] = *(const bf16x8*)(wt);
        dst[1] = *(const bf16x8*)(wt + 128);
        dst[2] = *(const bf16x8*)(wt + 256);
        dst[3] = *(const bf16x8*)(wt + 384);
    };

#define DO_TAP(KY, KX, A) do {                                                 \
        bf16x8 bfv[4];                                                         \
        _Pragma("unroll")                                                      \
        for (int n = 0; n < 4; ++n)                                            \
            bfv[n] = *(const bf16x8*)(sxp +                                    \
                        ((KY)*4*SXSTRIDE + (KX) + n*16) * 8);                  \
        _Pragma("unroll")                                                      \
        for (int m = 0; m < 4; ++m)                                            \
            _Pragma("unroll")                                                  \
            for (int n = 0; n < 4; ++n)                                        \
                acc[m][n] = __builtin_amdgcn_mfma_f32_16x16x32_bf16(           \
                    A[m], bfv[n], acc[m][n], 0, 0, 0);                         \
    } while (0)

    // ---- prologue: X + A taps 0,1 for c4=0
    issue_x(0);
    loadA(A0, 0, 0);
    loadA(A1, 0, 1);
    write_x();
    __syncthreads();

    for (int c4 = 0; c4 < 4; ++c4) {
        if (c4 < 3) issue_x(c4 + 1);   // next X flies under the 9 taps

        DO_TAP(0, 0, A0); loadA(A0, c4, 2);
        DO_TAP(0, 1, A1); loadA(A1, c4, 3);
        DO_TAP(0, 2, A0); loadA(A0, c4, 4);
        DO_TAP(1, 0, A1); loadA(A1, c4, 5);
        DO_TAP(1, 1, A0); loadA(A0, c4, 6);
        DO_TAP(1, 2, A1); loadA(A1, c4, 7);
        DO_TAP(2, 0, A0); loadA(A0, c4, 8);
        DO_TAP(2, 1, A1);                       // consumed tap7 (loaded 2 ahead)
        DO_TAP(2, 2, A0);                       // consumed tap8

        if (c4 < 3) {
            loadA(A0, c4 + 1, 0);               // covered by barrier + write_x
            loadA(A1, c4 + 1, 1);
            __syncthreads();                    // all waves done reading sx
            write_x();
            __syncthreads();                    // sx ready for next c4
        }
    }
#undef DO_TAP

    // ---- epilogue: D[row=oc=(l>>4)*4+r][col=pix=l&15]
    #pragma unroll
    for (int m = 0; m < 4; ++m) {
        int ocb = woc * 64 + m * 16 + l4 * 4;
        #pragma unroll
        for (int r = 0; r < 4; ++r) {
            float* orow = out + ((b * NOC + ocb + r) * NF + y) * NT + t0;
            #pragma unroll
            for (int n = 0; n < 4; ++n)
                orow[wpix * 64 + n * 16 + l15] = acc[m][n][r];
        }
    }
}

extern "C" void kernel_launch(void* const* d_in, const int* in_sizes, int n_in,
                              void* d_out, int out_size, void* d_ws, size_t ws_size,
                              hipStream_t stream) {
    const float* x    = (const float*)d_in[0];
    const float* g    = (const float*)d_in[1];
    const float* dk   = (const float*)d_in[2];
    const float* bias = (const float*)d_in[3];
    const float* w    = (const float*)d_in[4];
    float* out = (float*)d_out;

    float* att = (float*)d_ws;                                  // 64 floats
    unsigned short* wb = (unsigned short*)((char*)d_ws + 256);  // 16*9*128*128 bf16, K-major

    attn_kernel<<<dim3(1), dim3(64), 0, stream>>>(g, dk, bias, att);
    agg_kernel<<<dim3(1024), dim3(256), 0, stream>>>(w, att, wb);
    conv_kernel<<<dim3(2048), dim3(256), 0, stream>>>(x, wb, out);
}